// Round 6
// baseline (614.655 us; speedup 1.0000x reference)
//
#include <hip/hip_runtime.h>
#include <hip/hip_fp16.h>

#define NFEAT 5
#define HID 64
#define BSH 9               // dst bucket = dst >> 9  (512 nodes/bucket)
#define BNODES 512
#define MAXBK 256           // max buckets (n <= 131072)
#define PSH 14              // src partition = src >> 14 (8 parts, n <= 131072)
#define NPART 8
#define CHUNK 4096          // edges per bin/hist block

__global__ void k_zero(int* p, int n) {
    int i = blockIdx.x * blockDim.x + threadIdx.x;
    if (i < n) p[i] = 0;
}

// ---- bucket histogram (dst>>9), LDS-merged ----
__global__ __launch_bounds__(256) void
k_bhist(const int* __restrict__ dst, int* bhist, int E) {
    __shared__ int h[MAXBK];
    int t = threadIdx.x;
    h[t] = 0;
    __syncthreads();
    int i0 = blockIdx.x * CHUNK;
    int i1 = i0 + CHUNK; if (i1 > E) i1 = E;
    for (int i = i0 + t; i < i1; i += 256) atomicAdd(&h[dst[i] >> BSH], 1);
    __syncthreads();
    if (h[t]) atomicAdd(&bhist[t], h[t]);
}

// ---- scan 256 bucket counts -> bbase[257], bcur ----
__global__ void k_bscan(const int* __restrict__ bhist, int* bbase, int* bcur) {
    __shared__ int sh[MAXBK];
    int t = threadIdx.x;
    int v = bhist[t];
    sh[t] = v;
    __syncthreads();
    for (int off = 1; off < 256; off <<= 1) {
        int a = (t >= off) ? sh[t - off] : 0;
        __syncthreads();
        sh[t] += a;
        __syncthreads();
    }
    int excl = sh[t] - v;
    bbase[t] = excl;
    bcur[t]  = excl;
    if (t == 255) bbase[256] = sh[255];
}

// ---- bin edges by dst-bucket (bucket-contiguous runs in `binned`) ----
__global__ __launch_bounds__(256) void
k_bin(const int* __restrict__ src, const int* __restrict__ dst,
      int* bcur, int2* __restrict__ binned, int E) {
    __shared__ int2 stg[CHUNK];
    __shared__ int hist[MAXBK], base[MAXBK], gb[MAXBK];
    int t = threadIdx.x;
    int e0 = blockIdx.x * CHUNK;
    int cc = E - e0; if (cc > CHUNK) cc = CHUNK;
    hist[t] = 0;
    __syncthreads();
    int2 my[CHUNK / 256]; int mb[CHUNK / 256];
#pragma unroll
    for (int k = 0; k < CHUNK / 256; ++k) {
        int i = e0 + k * 256 + t;
        if (i < E) {
            my[k].x = src[i]; my[k].y = dst[i];
            mb[k] = my[k].y >> BSH;
            atomicAdd(&hist[mb[k]], 1);
        } else mb[k] = -1;
    }
    __syncthreads();
    int c = hist[t];
    base[t] = c;
    __syncthreads();
    for (int off = 1; off < 256; off <<= 1) {
        int a = (t >= off) ? base[t - off] : 0;
        __syncthreads();
        base[t] += a;
        __syncthreads();
    }
    int excl = base[t] - c;
    base[t] = excl;
    gb[t] = c ? atomicAdd(&bcur[t], c) : 0;
    hist[t] = 0;   // reuse as placement cursor
    __syncthreads();
#pragma unroll
    for (int k = 0; k < CHUNK / 256; ++k) {
        if (mb[k] >= 0) {
            int p = base[mb[k]] + atomicAdd(&hist[mb[k]], 1);
            stg[p] = my[k];
        }
    }
    __syncthreads();
#pragma unroll
    for (int k = 0; k < CHUNK / 256; ++k) {
        int p = k * 256 + t;
        if (p < cc) {
            int2 v = stg[p];
            int b = v.y >> BSH;
            binned[gb[b] + (p - base[b])] = v;
        }
    }
}

// ---- per-bucket LDS counting sort over (srcpart, local dst):
//      emits csr, rpS[p*n+v], lenS[p*n+v], and dis[v] ----
__global__ __launch_bounds__(256) void
k_sort(const int2* __restrict__ binned, const int* __restrict__ bbase,
       int* __restrict__ rpS, int* __restrict__ lenS,
       int* __restrict__ csr, float* __restrict__ dis, int n) {
    __shared__ int hist[NPART * BNODES];   // 4096
    __shared__ int cur[NPART * BNODES];
    __shared__ int tmp[256];
    int t = threadIdx.x, b = blockIdx.x;
    int e0 = bbase[b], e1 = bbase[b + 1];
    int v0 = b << BSH;
    int nv = n - v0; if (nv > BNODES) nv = BNODES;
#pragma unroll
    for (int k = 0; k < 16; ++k) hist[k * 256 + t] = 0;
    __syncthreads();
    for (int i = e0 + t; i < e1; i += 256) {
        int2 ed = binned[i];
        int bin = ((ed.x >> PSH) << BSH) | (ed.y - v0);
        atomicAdd(&hist[bin], 1);
    }
    __syncthreads();
    // degree -> dis
    for (int vl = t; vl < nv; vl += 256) {
        int d = 0;
#pragma unroll
        for (int p = 0; p < NPART; ++p) d += hist[p * BNODES + vl];
        dis[v0 + vl] = rsqrtf((float)d + 1.0f);
    }
    // exclusive scan of 4096 bins (16 bins/thread + block scan)
    int s = 0, b0 = t * 16;
#pragma unroll
    for (int k = 0; k < 16; ++k) { cur[b0 + k] = s; s += hist[b0 + k]; }
    tmp[t] = s;
    __syncthreads();
    for (int off = 1; off < 256; off <<= 1) {
        int a = (t >= off) ? tmp[t - off] : 0;
        __syncthreads();
        tmp[t] += a;
        __syncthreads();
    }
    int add = e0 + tmp[t] - s;
#pragma unroll
    for (int k = 0; k < 16; ++k) cur[b0 + k] += add;
#pragma unroll
    for (int k = 0; k < 16; ++k) {
        int bin = b0 + k, p = bin >> BSH, vl = bin & (BNODES - 1);
        if (vl < nv) {
            rpS[p * n + v0 + vl]  = cur[bin];
            lenS[p * n + v0 + vl] = hist[bin];
        }
    }
    __syncthreads();
    for (int i = e0 + t; i < e1; i += 256) {
        int2 ed = binned[i];
        int bin = ((ed.x >> PSH) << BSH) | (ed.y - v0);
        int pos = atomicAdd(&cur[bin], 1);
        csr[pos] = ed.x;
    }
}

__global__ void k_xscale(const float* __restrict__ x, const float* __restrict__ dis,
                         float* __restrict__ xs, int n) {
    int i = blockIdx.x * blockDim.x + threadIdx.x;
    if (i >= n) return;
    float d = dis[i];
#pragma unroll
    for (int c = 0; c < NFEAT; ++c) xs[i * NFEAT + c] = d * x[i * NFEAT + c];
}

// ---- layer 1: wave/node, lane-strided over concatenated sub-rows ----
__global__ __launch_bounds__(256) void
k_layer1(const int* __restrict__ rpS, const int* __restrict__ lenS,
         const int* __restrict__ csr, const float* __restrict__ xs,
         const float* __restrict__ dis, const float* __restrict__ W1,
         const float* __restrict__ b1, __half* __restrict__ g1h, int n) {
    int wave = (blockIdx.x * blockDim.x + threadIdx.x) >> 6;
    int lane = threadIdx.x & 63;
    if (wave >= n) return;
    int v = wave;
    int sA = 0, lA = 0;
    if (lane < NPART) { sA = rpS[lane * n + v]; lA = lenS[lane * n + v]; }
    int S0=__shfl(sA,0,64),S1=__shfl(sA,1,64),S2=__shfl(sA,2,64),S3=__shfl(sA,3,64),
        S4=__shfl(sA,4,64),S5=__shfl(sA,5,64),S6=__shfl(sA,6,64),S7=__shfl(sA,7,64);
    int L0=__shfl(lA,0,64),L1=__shfl(lA,1,64),L2=__shfl(lA,2,64),L3=__shfl(lA,3,64),
        L4=__shfl(lA,4,64),L5=__shfl(lA,5,64),L6=__shfl(lA,6,64);
    int P1=L0,P2=P1+L1,P3=P2+L2,P4=P3+L3,P5=P4+L4,P6=P5+L5,P7=P6+L6,P8=P7+__shfl(lA,7,64);
    float a0=0,a1=0,a2=0,a3=0,a4=0;
    for (int j = lane; j < P8; j += 64) {
        int st=S0, off=j;
        if (j>=P1){st=S1;off=j-P1;}
        if (j>=P2){st=S2;off=j-P2;}
        if (j>=P3){st=S3;off=j-P3;}
        if (j>=P4){st=S4;off=j-P4;}
        if (j>=P5){st=S5;off=j-P5;}
        if (j>=P6){st=S6;off=j-P6;}
        if (j>=P7){st=S7;off=j-P7;}
        int s = csr[st + off];
        const float* q = xs + (size_t)s * NFEAT;
        a0+=q[0]; a1+=q[1]; a2+=q[2]; a3+=q[3]; a4+=q[4];
    }
#pragma unroll
    for (int m = 32; m > 0; m >>= 1) {
        a0 += __shfl_xor(a0,m,64); a1 += __shfl_xor(a1,m,64);
        a2 += __shfl_xor(a2,m,64); a3 += __shfl_xor(a3,m,64);
        a4 += __shfl_xor(a4,m,64);
    }
    float dv = dis[v];
    const float* pv = xs + (size_t)v * NFEAT;
    a0 = dv*(a0+pv[0]); a1 = dv*(a1+pv[1]); a2 = dv*(a2+pv[2]);
    a3 = dv*(a3+pv[3]); a4 = dv*(a4+pv[4]);
    int c = lane;
    float h = b1[c] + a0*W1[c] + a1*W1[64+c] + a2*W1[128+c]
            + a3*W1[192+c] + a4*W1[256+c];
    g1h[(size_t)v * HID + c] = __float2half(dv * fmaxf(h, 0.0f));
}

// ---- layer 2+3: 16 nodes/wave, partition-swept gather (L2-resident window) ----
__global__ __launch_bounds__(256) void
k_layer23(const int* __restrict__ rpS, const int* __restrict__ lenS,
          const int* __restrict__ csr, const __half* __restrict__ g1h,
          const float* __restrict__ dis, const float* __restrict__ W2,
          const float* __restrict__ b2, const float* __restrict__ W3,
          float* __restrict__ svs, int n) {
    __shared__ float W2s[HID * HID];
    for (int i = threadIdx.x; i < HID * HID; i += 256) W2s[i] = W2[i];
    __syncthreads();
    int wave = (blockIdx.x * blockDim.x + threadIdx.x) >> 6;
    int lane = threadIdx.x & 63;
    int v0 = wave * 16;
    if (v0 >= n) return;
    float acc[16];
#pragma unroll
    for (int i = 0; i < 16; ++i) {
        int vi = v0 + i; if (vi >= n) vi = n - 1;
        acc[i] = __half2float(g1h[(size_t)vi * HID + lane]);   // self term
    }
    float dvv;
    { int vi = v0 + (lane & 15); if (vi >= n) vi = n - 1; dvv = dis[vi]; }
    for (int p = 0; p < NPART; ++p) {
        int sA = 0, lA = 0;
        if (lane < 16) {
            int vi = v0 + lane;
            if (vi < n) { sA = rpS[p * n + vi]; lA = lenS[p * n + vi]; }
        }
#pragma unroll
        for (int i = 0; i < 16; ++i) {
            int st = __shfl(sA, i, 64), ln = __shfl(lA, i, 64);
            int e = 0;
            for (; e + 4 <= ln; e += 4) {
                int q0=csr[st+e], q1=csr[st+e+1], q2=csr[st+e+2], q3=csr[st+e+3];
                float f0=__half2float(g1h[(size_t)q0*HID+lane]);
                float f1=__half2float(g1h[(size_t)q1*HID+lane]);
                float f2=__half2float(g1h[(size_t)q2*HID+lane]);
                float f3=__half2float(g1h[(size_t)q3*HID+lane]);
                acc[i] += (f0+f1)+(f2+f3);
            }
            for (; e < ln; ++e)
                acc[i] += __half2float(g1h[(size_t)csr[st+e]*HID+lane]);
        }
    }
    float bb = b2[lane], w3 = W3[lane];
#pragma unroll
    for (int i = 0; i < 16; ++i) {
        float dv = __shfl(dvv, i, 64);
        float a = acc[i] * dv;
        float o = bb;
#pragma unroll
        for (int k = 0; k < 64; ++k)
            o = fmaf(__shfl(a, k, 64), W2s[(k << 6) + lane], o);
        o = fmaxf(o, 0.0f);
        float val = o * w3;
#pragma unroll
        for (int m = 32; m > 0; m >>= 1) val += __shfl_xor(val, m, 64);
        if (lane == 0 && v0 + i < n) svs[v0 + i] = dv * val;
    }
}

// ---- output: wave/node scalar gather over concatenated sub-rows ----
__global__ __launch_bounds__(256) void
k_out(const int* __restrict__ rpS, const int* __restrict__ lenS,
      const int* __restrict__ csr, const float* __restrict__ svs,
      const float* __restrict__ dis, const float* __restrict__ b3,
      float* __restrict__ out, int n) {
    int wave = (blockIdx.x * blockDim.x + threadIdx.x) >> 6;
    int lane = threadIdx.x & 63;
    if (wave >= n) return;
    int v = wave;
    int sA = 0, lA = 0;
    if (lane < NPART) { sA = rpS[lane * n + v]; lA = lenS[lane * n + v]; }
    int S0=__shfl(sA,0,64),S1=__shfl(sA,1,64),S2=__shfl(sA,2,64),S3=__shfl(sA,3,64),
        S4=__shfl(sA,4,64),S5=__shfl(sA,5,64),S6=__shfl(sA,6,64),S7=__shfl(sA,7,64);
    int L0=__shfl(lA,0,64),L1=__shfl(lA,1,64),L2=__shfl(lA,2,64),L3=__shfl(lA,3,64),
        L4=__shfl(lA,4,64),L5=__shfl(lA,5,64),L6=__shfl(lA,6,64);
    int P1=L0,P2=P1+L1,P3=P2+L2,P4=P3+L3,P5=P4+L4,P6=P5+L5,P7=P6+L6,P8=P7+__shfl(lA,7,64);
    float acc = 0.f;
    for (int j = lane; j < P8; j += 64) {
        int st=S0, off=j;
        if (j>=P1){st=S1;off=j-P1;}
        if (j>=P2){st=S2;off=j-P2;}
        if (j>=P3){st=S3;off=j-P3;}
        if (j>=P4){st=S4;off=j-P4;}
        if (j>=P5){st=S5;off=j-P5;}
        if (j>=P6){st=S6;off=j-P6;}
        if (j>=P7){st=S7;off=j-P7;}
        acc += svs[csr[st + off]];
    }
#pragma unroll
    for (int m = 32; m > 0; m >>= 1) acc += __shfl_xor(acc, m, 64);
    if (lane == 0) out[v] = b3[0] + dis[v] * (acc + svs[v]);
}

extern "C" void kernel_launch(void* const* d_in, const int* in_sizes, int n_in,
                              void* d_out, int out_size, void* d_ws, size_t ws_size,
                              hipStream_t stream) {
    const float* x  = (const float*)d_in[0];
    const int*   ei = (const int*)d_in[1];
    const float* W1 = (const float*)d_in[2];
    const float* b1 = (const float*)d_in[3];
    const float* W2 = (const float*)d_in[4];
    const float* b2 = (const float*)d_in[5];
    const float* W3 = (const float*)d_in[6];
    const float* b3 = (const float*)d_in[7];
    float* out = (float*)d_out;

    const int n = out_size;           // 100000
    const int E = in_sizes[1] / 2;    // 3200000
    const int* src = ei;
    const int* dst = ei + E;

    // ws layout (int units):
    // [0,256) bhist | [256,513) bbase | [528,784) bcur | [1024, +8n) rpS | +8n lenS
    // | +n dis | +n svs | +E csr | +2E binned (g1h aliases low 32n ints; xs at +32n, 5n floats)
    int*    bhist  = (int*)d_ws;
    int*    bbase  = bhist + 256;
    int*    bcur   = bhist + 528;
    int*    rpS    = bhist + 1024;
    int*    lenS   = rpS + (size_t)8 * n;
    float*  dis    = (float*)(lenS + (size_t)8 * n);
    float*  svs    = dis + n;
    int*    csr    = (int*)(svs + n);
    int2*   binned = (int2*)(csr + E);
    __half* g1h    = (__half*)binned;
    float*  xs     = (float*)binned + (size_t)32 * n;

    const int B = 256;
    const int nchunk = (E + CHUNK - 1) / CHUNK;
    const int nbk    = (n + BNODES - 1) / BNODES;
    const int gridW  = ((size_t)n * 64 + B - 1) / B;         // wave per node
    const int grid23 = (((n + 15) / 16) * 64 + B - 1) / B;   // wave per 16 nodes

    k_zero   <<<1, 256, 0, stream>>>(bhist, 256);
    k_bhist  <<<nchunk, 256, 0, stream>>>(dst, bhist, E);
    k_bscan  <<<1, 256, 0, stream>>>(bhist, bbase, bcur);
    k_bin    <<<nchunk, 256, 0, stream>>>(src, dst, bcur, binned, E);
    k_sort   <<<nbk, 256, 0, stream>>>(binned, bbase, rpS, lenS, csr, dis, n);
    k_xscale <<<(n + B - 1) / B, B, 0, stream>>>(x, dis, xs, n);
    k_layer1 <<<gridW, B, 0, stream>>>(rpS, lenS, csr, xs, dis, W1, b1, g1h, n);
    k_layer23<<<grid23, B, 0, stream>>>(rpS, lenS, csr, g1h, dis, W2, b2, W3, svs, n);
    k_out    <<<gridW, B, 0, stream>>>(rpS, lenS, csr, svs, dis, b3, out, n);
}

// Round 7
// 418.861 us; speedup vs baseline: 1.4674x; 1.4674x over previous
//
#include <hip/hip_runtime.h>
#include <hip/hip_fp16.h>

#define NFEAT 5
#define HID 64
#define BSH 9               // dst bucket = dst >> 9  (512 nodes/bucket)
#define BNODES 512
#define MAXBK 256           // max buckets (n <= 131072)
#define PSH 14              // src partition = src >> 14 (8 parts, n <= 131072)
#define NPART 8
#define CHUNK 4096          // edges per bin/hist block

__global__ void k_zero(int* p, int n) {
    int i = blockIdx.x * blockDim.x + threadIdx.x;
    if (i < n) p[i] = 0;
}

// ---- bucket histogram (dst>>9), LDS-merged ----
__global__ __launch_bounds__(256) void
k_bhist(const int* __restrict__ dst, int* bhist, int E) {
    __shared__ int h[MAXBK];
    int t = threadIdx.x;
    h[t] = 0;
    __syncthreads();
    int i0 = blockIdx.x * CHUNK;
    int i1 = i0 + CHUNK; if (i1 > E) i1 = E;
    for (int i = i0 + t; i < i1; i += 256) atomicAdd(&h[dst[i] >> BSH], 1);
    __syncthreads();
    if (h[t]) atomicAdd(&bhist[t], h[t]);
}

// ---- scan 256 bucket counts -> bbase[257], bcur ----
__global__ void k_bscan(const int* __restrict__ bhist, int* bbase, int* bcur) {
    __shared__ int sh[MAXBK];
    int t = threadIdx.x;
    int v = bhist[t];
    sh[t] = v;
    __syncthreads();
    for (int off = 1; off < 256; off <<= 1) {
        int a = (t >= off) ? sh[t - off] : 0;
        __syncthreads();
        sh[t] += a;
        __syncthreads();
    }
    int excl = sh[t] - v;
    bbase[t] = excl;
    bcur[t]  = excl;
    if (t == 255) bbase[256] = sh[255];
}

// ---- bin edges by dst-bucket (bucket-contiguous runs in `binned`) ----
__global__ __launch_bounds__(256) void
k_bin(const int* __restrict__ src, const int* __restrict__ dst,
      int* bcur, int2* __restrict__ binned, int E) {
    __shared__ int2 stg[CHUNK];
    __shared__ int hist[MAXBK], base[MAXBK], gb[MAXBK];
    int t = threadIdx.x;
    int e0 = blockIdx.x * CHUNK;
    int cc = E - e0; if (cc > CHUNK) cc = CHUNK;
    hist[t] = 0;
    __syncthreads();
    int2 my[CHUNK / 256]; int mb[CHUNK / 256];
#pragma unroll
    for (int k = 0; k < CHUNK / 256; ++k) {
        int i = e0 + k * 256 + t;
        if (i < E) {
            my[k].x = src[i]; my[k].y = dst[i];
            mb[k] = my[k].y >> BSH;
            atomicAdd(&hist[mb[k]], 1);
        } else mb[k] = -1;
    }
    __syncthreads();
    int c = hist[t];
    base[t] = c;
    __syncthreads();
    for (int off = 1; off < 256; off <<= 1) {
        int a = (t >= off) ? base[t - off] : 0;
        __syncthreads();
        base[t] += a;
        __syncthreads();
    }
    int excl = base[t] - c;
    base[t] = excl;
    gb[t] = c ? atomicAdd(&bcur[t], c) : 0;
    hist[t] = 0;   // reuse as placement cursor
    __syncthreads();
#pragma unroll
    for (int k = 0; k < CHUNK / 256; ++k) {
        if (mb[k] >= 0) {
            int p = base[mb[k]] + atomicAdd(&hist[mb[k]], 1);
            stg[p] = my[k];
        }
    }
    __syncthreads();
#pragma unroll
    for (int k = 0; k < CHUNK / 256; ++k) {
        int p = k * 256 + t;
        if (p < cc) {
            int2 v = stg[p];
            int b = v.y >> BSH;
            binned[gb[b] + (p - base[b])] = v;
        }
    }
}

// ---- per-bucket LDS counting sort, bins = (local dst)<<3 | srcpart:
//      rows come out CONTIGUOUS and partition-sorted; emits rpN, dis, csr ----
__global__ __launch_bounds__(256) void
k_sort(const int2* __restrict__ binned, const int* __restrict__ bbase,
       int* __restrict__ rpN, int* __restrict__ csr, float* __restrict__ dis,
       int n, int nbk) {
    __shared__ int hist[NPART * BNODES];   // 4096
    __shared__ int cur[NPART * BNODES];
    __shared__ int tmp[256];
    int t = threadIdx.x, b = blockIdx.x;
    int e0 = bbase[b], e1 = bbase[b + 1];
    int v0 = b << BSH;
    int nv = n - v0; if (nv > BNODES) nv = BNODES;
#pragma unroll
    for (int k = 0; k < 16; ++k) hist[k * 256 + t] = 0;
    __syncthreads();
    for (int i = e0 + t; i < e1; i += 256) {
        int2 ed = binned[i];
        int bin = ((ed.y - v0) << 3) | (ed.x >> PSH);   // node-major, partition-minor
        atomicAdd(&hist[bin], 1);
    }
    __syncthreads();
    // degree -> dis
    for (int vl = t; vl < nv; vl += 256) {
        int d = 0;
#pragma unroll
        for (int p = 0; p < NPART; ++p) d += hist[(vl << 3) + p];
        dis[v0 + vl] = rsqrtf((float)d + 1.0f);
    }
    // exclusive scan of 4096 bins (16 bins/thread + block scan)
    int s = 0, b0 = t * 16;
#pragma unroll
    for (int k = 0; k < 16; ++k) { cur[b0 + k] = s; s += hist[b0 + k]; }
    tmp[t] = s;
    __syncthreads();
    for (int off = 1; off < 256; off <<= 1) {
        int a = (t >= off) ? tmp[t - off] : 0;
        __syncthreads();
        tmp[t] += a;
        __syncthreads();
    }
    int add = e0 + tmp[t] - s;
#pragma unroll
    for (int k = 0; k < 16; ++k) cur[b0 + k] += add;
    // row starts: bin with p==0 is the row head
#pragma unroll
    for (int k = 0; k < 16; ++k) {
        int bin = b0 + k;
        if ((bin & 7) == 0) {
            int vl = bin >> 3;
            if (vl < nv) rpN[v0 + vl] = cur[bin];
        }
    }
    if (b == nbk - 1 && t == 0) rpN[n] = e1;
    __syncthreads();
    for (int i = e0 + t; i < e1; i += 256) {
        int2 ed = binned[i];
        int bin = ((ed.y - v0) << 3) | (ed.x >> PSH);
        int pos = atomicAdd(&cur[bin], 1);
        csr[pos] = ed.x;
    }
}

__global__ void k_xscale(const float* __restrict__ x, const float* __restrict__ dis,
                         float* __restrict__ xs, int n) {
    int i = blockIdx.x * blockDim.x + threadIdx.x;
    if (i >= n) return;
    float d = dis[i];
#pragma unroll
    for (int c = 0; c < NFEAT; ++c) xs[i * NFEAT + c] = d * x[i * NFEAT + c];
}

// ---- layer 1: wave/node, lane-strided gather over contiguous row ----
__global__ __launch_bounds__(256) void
k_layer1(const int* __restrict__ rpN, const int* __restrict__ csr,
         const float* __restrict__ xs, const float* __restrict__ dis,
         const float* __restrict__ W1, const float* __restrict__ b1,
         __half* __restrict__ g1h, int n) {
    int wave = (blockIdx.x * blockDim.x + threadIdx.x) >> 6;
    int lane = threadIdx.x & 63;
    if (wave >= n) return;
    int v = wave;
    int r0 = rpN[v], r1 = rpN[v + 1];
    float a0 = 0.f, a1 = 0.f, a2 = 0.f, a3 = 0.f, a4 = 0.f;
    for (int j = r0 + lane; j < r1; j += 64) {
        const float* p = xs + (size_t)csr[j] * NFEAT;
        a0 += p[0]; a1 += p[1]; a2 += p[2]; a3 += p[3]; a4 += p[4];
    }
#pragma unroll
    for (int m = 32; m > 0; m >>= 1) {
        a0 += __shfl_xor(a0, m, 64); a1 += __shfl_xor(a1, m, 64);
        a2 += __shfl_xor(a2, m, 64); a3 += __shfl_xor(a3, m, 64);
        a4 += __shfl_xor(a4, m, 64);
    }
    float dv = dis[v];
    const float* pv = xs + (size_t)v * NFEAT;
    a0 = dv * (a0 + pv[0]); a1 = dv * (a1 + pv[1]); a2 = dv * (a2 + pv[2]);
    a3 = dv * (a3 + pv[3]); a4 = dv * (a4 + pv[4]);
    int c = lane;
    float h = b1[c] + a0 * W1[c] + a1 * W1[64 + c] + a2 * W1[128 + c]
            + a3 * W1[192 + c] + a4 * W1[256 + c];
    g1h[(size_t)v * HID + c] = __float2half(dv * fmaxf(h, 0.0f));
}

// ---- layer 2+3: wave/node, unroll-8 half gathers over partition-sorted row ----
__global__ __launch_bounds__(256) void
k_layer23(const int* __restrict__ rpN, const int* __restrict__ csr,
          const __half* __restrict__ g1h, const float* __restrict__ dis,
          const float* __restrict__ W2, const float* __restrict__ b2,
          const float* __restrict__ W3, float* __restrict__ svs, int n) {
    __shared__ float W2s[HID * HID];
    for (int i = threadIdx.x; i < HID * HID; i += 256) W2s[i] = W2[i];
    __syncthreads();
    int wave = (blockIdx.x * blockDim.x + threadIdx.x) >> 6;
    int lane = threadIdx.x & 63;
    if (wave >= n) return;
    int v = wave;
    int r0 = rpN[v], r1 = rpN[v + 1];
    float acc = __half2float(g1h[(size_t)v * HID + lane]);   // self term
    int j = r0;
    for (; j + 8 <= r1; j += 8) {
        int s0 = csr[j],     s1 = csr[j + 1], s2 = csr[j + 2], s3 = csr[j + 3];
        int s4 = csr[j + 4], s5 = csr[j + 5], s6 = csr[j + 6], s7 = csr[j + 7];
        float t0 = __half2float(g1h[(size_t)s0 * HID + lane]);
        float t1 = __half2float(g1h[(size_t)s1 * HID + lane]);
        float t2 = __half2float(g1h[(size_t)s2 * HID + lane]);
        float t3 = __half2float(g1h[(size_t)s3 * HID + lane]);
        float t4 = __half2float(g1h[(size_t)s4 * HID + lane]);
        float t5 = __half2float(g1h[(size_t)s5 * HID + lane]);
        float t6 = __half2float(g1h[(size_t)s6 * HID + lane]);
        float t7 = __half2float(g1h[(size_t)s7 * HID + lane]);
        acc += ((t0 + t1) + (t2 + t3)) + ((t4 + t5) + (t6 + t7));
    }
    for (; j < r1; ++j) acc += __half2float(g1h[(size_t)csr[j] * HID + lane]);
    float dv = dis[v];
    acc *= dv;                                     // agg2[v, lane]
    float out = b2[lane];
#pragma unroll
    for (int k = 0; k < HID; ++k)
        out = fmaf(__shfl(acc, k, 64), W2s[(k << 6) + lane], out);
    out = fmaxf(out, 0.0f);
    float val = out * W3[lane];
#pragma unroll
    for (int m = 32; m > 0; m >>= 1) val += __shfl_xor(val, m, 64);
    if (lane == 0) svs[v] = dv * val;              // pre-scaled for output gather
}

// ---- output: wave/node scalar gather over contiguous row ----
__global__ __launch_bounds__(256) void
k_out(const int* __restrict__ rpN, const int* __restrict__ csr,
      const float* __restrict__ svs, const float* __restrict__ dis,
      const float* __restrict__ b3, float* __restrict__ out, int n) {
    int wave = (blockIdx.x * blockDim.x + threadIdx.x) >> 6;
    int lane = threadIdx.x & 63;
    if (wave >= n) return;
    int v = wave;
    int r0 = rpN[v], r1 = rpN[v + 1];
    float acc = (lane == 0) ? svs[v] : 0.f;        // self term
    for (int j = r0 + lane; j < r1; j += 64) acc += svs[csr[j]];
#pragma unroll
    for (int m = 32; m > 0; m >>= 1) acc += __shfl_xor(acc, m, 64);
    if (lane == 0) out[v] = b3[0] + dis[v] * acc;
}

extern "C" void kernel_launch(void* const* d_in, const int* in_sizes, int n_in,
                              void* d_out, int out_size, void* d_ws, size_t ws_size,
                              hipStream_t stream) {
    const float* x  = (const float*)d_in[0];
    const int*   ei = (const int*)d_in[1];
    const float* W1 = (const float*)d_in[2];
    const float* b1 = (const float*)d_in[3];
    const float* W2 = (const float*)d_in[4];
    const float* b2 = (const float*)d_in[5];
    const float* W3 = (const float*)d_in[6];
    const float* b3 = (const float*)d_in[7];
    float* out = (float*)d_out;

    const int n = out_size;           // 100000
    const int E = in_sizes[1] / 2;    // 3200000
    const int* src = ei;
    const int* dst = ei + E;

    // ws layout (int units):
    // bhist[256] bbase[257] pad bcur[256] | rpN[n+1] | dis[n] | svs[n] | csr[E]
    // | binned[2E ints] (g1h aliases low 32n ints; xs in the tail above 32n)
    int*    bhist  = (int*)d_ws;
    int*    bbase  = bhist + 256;
    int*    bcur   = bhist + 520;
    int*    rpN    = bhist + 1024;
    float*  dis    = (float*)(rpN + n + 1);
    float*  svs    = dis + n;
    int*    csr    = (int*)(svs + n);
    int2*   binned = (int2*)(csr + E);
    __half* g1h    = (__half*)binned;
    float*  xs     = (float*)binned + (size_t)32 * n;

    const int B = 256;
    const int nchunk = (E + CHUNK - 1) / CHUNK;
    const int nbk    = (n + BNODES - 1) / BNODES;
    const int gridW  = ((size_t)n * 64 + B - 1) / B;   // wave per node

    k_zero   <<<1, 256, 0, stream>>>(bhist, 256);
    k_bhist  <<<nchunk, 256, 0, stream>>>(dst, bhist, E);
    k_bscan  <<<1, 256, 0, stream>>>(bhist, bbase, bcur);
    k_bin    <<<nchunk, 256, 0, stream>>>(src, dst, bcur, binned, E);
    k_sort   <<<nbk, 256, 0, stream>>>(binned, bbase, rpN, csr, dis, n, nbk);
    k_xscale <<<(n + B - 1) / B, B, 0, stream>>>(x, dis, xs, n);
    k_layer1 <<<gridW, B, 0, stream>>>(rpN, csr, xs, dis, W1, b1, g1h, n);
    k_layer23<<<gridW, B, 0, stream>>>(rpN, csr, g1h, dis, W2, b2, W3, svs, n);
    k_out    <<<gridW, B, 0, stream>>>(rpN, csr, svs, dis, b3, out, n);
}